// Round 15
// baseline (165.925 us; speedup 1.0000x reference)
//
#include <hip/hip_runtime.h>
#include <cmath>

// GRNN_3547642986522 — B=4096 filters, T=2048 steps. R15 = R11 + NT stores.
// Math: cov (Riccati) evolves by a CONSTANT LFT per step (Euler == Kalman LFT
// to O(dt^2)); host computes ML = M_step^32 in double. x is affine given cov;
// f linear; t closed-form.
// Mapping: wave = 1 batch, lane = 1 segment (64 segs x 32 steps).
//  - lane s: checkpoint cov/f at t=32s via per-lane binary matpow of ML;
//  - phase 1: accumulate segment transfer x_end = X x_start + Q (reads dy);
//  - wave-scan (6 shfl_up) composes the 64 affine maps -> x at segment start;
//  - phase 2: replay 32 steps emitting dy_hat; lane 63 writes nstate/fnew.
// Memory: wave covers one contiguous 16KB row; block = 4 rows, XCD-swizzled.
// dy read once (registers, reused both phases). dy_hat stored NONTEMPORAL:
// single-use output bypasses L2/L3 write-allocate so dy stays L3-resident
// across graph replays (R11 warm FETCH was 34MB = dy half-evicted by writes).

#define NBATCH 4096
#define NT     2048
#define ROWF4  1024        // float4 per dy row

struct M16 { float m[16]; };
typedef float f4v __attribute__((ext_vector_type(4)));

namespace gk {

constexpr float DT   = 0.001f;
constexpr float A00  = -0.15f;
constexpr float A01  = 6.283185f;
constexpr float A10  = -6.283185f;
constexpr float A11  = -0.15f;
constexpr float C0   = 1.6970562748477141f;
constexpr float DD   = 5.25f;

constexpr float P00c = 1.0f + DT*A00;
constexpr float P01c = DT*A01;
constexpr float P10c = DT*A10;
constexpr float P11c = 1.0f + DT*A11;
constexpr float DTC  = DT*C0;
constexpr float QQ   = DT*C0*C0;
constexpr float cVA  = 1.0f + 2.0f*DT*A00;
constexpr float cVB  = 2.0f*DT*A01;
constexpr float cVBn = 2.0f*DT*A10;
constexpr float cVD  = DT*DD;
constexpr float cCA  = 1.0f + DT*(A00+A11);
constexpr float cCB  = DT*A10;
constexpr float cCC  = DT*A01;
constexpr float YC   = C0*DT;

__device__ __forceinline__ void cov_step(float& vx, float& vp, float& cxp)
{
    float a1 = fmaf(-QQ, vx,  cVA);
    float b1 = fmaf(cVB, cxp, cVD);
    float a2 = fmaf(-QQ, cxp, cVBn);
    float b2 = fmaf(a2,  cxp, cVD);
    float a3 = fmaf(-QQ, vx,  cCA);
    float m  = cCC * vp;
    float c3 = fmaf(cCB, vx,  m);
    float nvx = fmaf(a1,  vx,  b1);
    float nvp = fmaf(cVA, vp,  b2);
    float ncx = fmaf(a3,  cxp, c3);
    vx = nvx; vp = nvp; cxp = ncx;
}

__device__ __forceinline__ void covf_step(
    float& vx, float& vp, float& cxp, float& f0, float& f1,
    float k00, float k01, float k10, float k11,
    float& xi0o, float& xi1o, float& nf0o)
{
    float xi0 = C0*vx, xi1 = C0*cxp;
    float nf0 = fmaf(DT, fmaf(k00, f0, k01*f1), f0);
    float nf1 = fmaf(DT, fmaf(k10, f0, k11*f1), f1);
    xi0o = xi0; xi1o = xi1; nf0o = nf0;
    cov_step(vx, vp, cxp);
    f0 = nf0; f1 = nf1;
}

__device__ __forceinline__ void mat4_mul(const float* A, const float* B, float* C)
{
    #pragma unroll
    for (int i = 0; i < 4; ++i)
        #pragma unroll
        for (int j = 0; j < 4; ++j) {
            float acc = A[i*4+0] * B[0*4+j];
            acc = fmaf(A[i*4+1], B[1*4+j], acc);
            acc = fmaf(A[i*4+2], B[2*4+j], acc);
            acc = fmaf(A[i*4+3], B[3*4+j], acc);
            C[i*4+j] = acc;
        }
}

// P -> (E P + F)(G P + H)^-1, P = [[vx,cxp],[cxp,vp]].
__device__ __forceinline__ void lft_apply(const float* m, float& vx, float& vp, float& cxp)
{
    float n00 = fmaf(m[0], vx,  fmaf(m[1], cxp, m[2]));
    float n01 = fmaf(m[0], cxp, fmaf(m[1], vp,  m[3]));
    float n10 = fmaf(m[4], vx,  fmaf(m[5], cxp, m[6]));
    float n11 = fmaf(m[4], cxp, fmaf(m[5], vp,  m[7]));
    float d00 = fmaf(m[8],  vx,  fmaf(m[9],  cxp, m[10]));
    float d01 = fmaf(m[8],  cxp, fmaf(m[9],  vp,  m[11]));
    float d10 = fmaf(m[12], vx,  fmaf(m[13], cxp, m[14]));
    float d11 = fmaf(m[12], cxp, fmaf(m[13], vp,  m[15]));
    float rdet = 1.0f / fmaf(d00, d11, -d01*d10);
    float p00 = fmaf(n00, d11, -n01*d10) * rdet;
    float p01 = fmaf(n01, d00, -n00*d01) * rdet;
    float p10 = fmaf(n10, d11, -n11*d10) * rdet;
    float p11 = fmaf(n11, d00, -n10*d01) * rdet;
    vx = p00; vp = p11; cxp = 0.5f*(p01 + p10);
}

// Per-lane checkpoint at segment start s: cov via lft(ML^s), f via Mf32^s.
__device__ __forceinline__ void seg_checkpoint(
    const M16& ml, int s,
    float k00, float k01, float k10, float k11,
    float& vx, float& vp, float& cxp, float& f0, float& f1)
{
    float acc[16] = {1,0,0,0, 0,1,0,0, 0,0,1,0, 0,0,0,1};
    float bas[16];
    #pragma unroll
    for (int i = 0; i < 16; ++i) bas[i] = ml.m[i];
    #pragma unroll
    for (int it = 0; it < 6; ++it) {
        float t[16];
        if ((s >> it) & 1) {
            mat4_mul(acc, bas, t);
            #pragma unroll
            for (int i = 0; i < 16; ++i) acc[i] = t[i];
        }
        if (it < 5) {
            mat4_mul(bas, bas, t);
            #pragma unroll
            for (int i = 0; i < 16; ++i) bas[i] = t[i];
        }
    }
    lft_apply(acc, vx, vp, cxp);

    float m00 = fmaf(DT,k00,1.f), m01 = DT*k01;
    float m10 = DT*k10,           m11 = fmaf(DT,k11,1.f);
    #pragma unroll
    for (int i = 0; i < 5; ++i) {            // (I + dt K)^32
        float a = fmaf(m00,m00, m01*m10);
        float q = fmaf(m00,m01, m01*m11);
        float c = fmaf(m10,m00, m11*m10);
        float d = fmaf(m10,m01, m11*m11);
        m00=a; m01=q; m10=c; m11=d;
    }
    float a00=1.f, a01=0.f, a10=0.f, a11=1.f;
    #pragma unroll
    for (int it = 0; it < 6; ++it) {
        if ((s >> it) & 1) {
            float x0 = fmaf(a00,m00, a01*m10);
            float x1 = fmaf(a00,m01, a01*m11);
            float x2 = fmaf(a10,m00, a11*m10);
            float x3 = fmaf(a10,m01, a11*m11);
            a00=x0; a01=x1; a10=x2; a11=x3;
        }
        if (it < 5) {
            float x0 = fmaf(m00,m00, m01*m10);
            float x1 = fmaf(m00,m01, m01*m11);
            float x2 = fmaf(m10,m00, m11*m10);
            float x3 = fmaf(m10,m01, m11*m11);
            m00=x0; m01=x1; m10=x2; m11=x3;
        }
    }
    float nf0 = fmaf(a00, f0, a01*f1);
    float nf1 = fmaf(a10, f0, a11*f1);
    f0 = nf0; f1 = nf1;
}

// XCD-aware bijective swizzle (n % 8 == 0).
__device__ __forceinline__ int xcd_swz(int bx, int n)
{
    return (bx & 7) * (n >> 3) + (bx >> 3);
}

} // namespace gk

// ------------------------------------------------------------- fused kernel
__global__ void __launch_bounds__(256, 3)
kfused(const float* __restrict__ dy, const float* __restrict__ state,
       const float* __restrict__ fin, const float* __restrict__ kp,
       M16 mc, float* __restrict__ out)
{
    using namespace gk;
    const int lane = threadIdx.x & 63;
    const int wv   = threadIdx.x >> 6;
    const int g    = xcd_swz(blockIdx.x, gridDim.x);   // 1024 blocks
    const int b    = g*4 + wv;                         // wave-uniform batch
    const int s    = lane;                             // lane = segment

    // Wave-uniform small loads (scalarized by compiler).
    const float k00 = kp[0], k01 = kp[1], k10 = kp[2], k11 = kp[3];
    const float x0i = state[b*6+0], x1i = state[b*6+1];
    const float vx0 = state[b*6+2], vp0 = state[b*6+3], cx0 = state[b*6+4];
    const float t0  = state[b*6+5];
    const float f0i = fin[b*2+0],   f1i = fin[b*2+1];

    // Load the lane's 256B dy slice (wave covers one contiguous 16KB row).
    const float4* base = reinterpret_cast<const float4*>(dy)
                       + (size_t)b*ROWF4 + s*16;
    float4 v[16];
    #pragma unroll
    for (int j = 0; j < 16; ++j) v[j] = base[j];

    // Checkpoint cov/f at segment start (hidden under load flight).
    float vx = vx0, vp = vp0, cxp = cx0, f0 = f0i, f1 = f1i;
    seg_checkpoint(mc, s, k00, k01, k10, k11, vx, vp, cxp, f0, f1);
    const float vxs = vx, vps = vp, cxs = cxp, f0s = f0, f1s = f1;

    // ---- Phase 1: per-segment affine map x_end = X x_start + Q.
    float X00 = 1.f, X01 = 0.f, X10 = 0.f, X11 = 1.f, Q0 = 0.f, Q1 = 0.f;
    #pragma unroll
    for (int j = 0; j < 16; ++j) {
        #pragma unroll
        for (int h = 0; h < 2; ++h) {
            float dy0 = h ? v[j].z : v[j].x;
            float xi0, xi1, nf0;
            covf_step(vx, vp, cxp, f0, f1, k00, k01, k10, k11, xi0, xi1, nf0);
            float p00 = fmaf(-DTC, xi0, P00c);
            float p10 = fmaf(-DTC, xi1, P10c);
            float r0  = xi0*dy0;
            float r1  = fmaf(DT, nf0, xi1*dy0);
            float nX00 = fmaf(p00, X00, P01c*X10);
            float nX01 = fmaf(p00, X01, P01c*X11);
            float nX10 = fmaf(p10, X00, P11c*X10);
            float nX11 = fmaf(p10, X01, P11c*X11);
            float nQ0  = fmaf(p00, Q0, fmaf(P01c, Q1, r0));
            float nQ1  = fmaf(p10, Q0, fmaf(P11c, Q1, r1));
            X00 = nX00; X01 = nX01; X10 = nX10; X11 = nX11; Q0 = nQ0; Q1 = nQ1;
        }
    }

    // ---- Wave-scan: inclusive prefix composition of the 64 affine maps.
    float A00 = X00, A01 = X01, A10 = X10, A11 = X11, B0 = Q0, B1 = Q1;
    #pragma unroll
    for (int d = 1; d < 64; d <<= 1) {
        float r00 = __shfl_up(A00, d);
        float r01 = __shfl_up(A01, d);
        float r10 = __shfl_up(A10, d);
        float r11 = __shfl_up(A11, d);
        float rB0 = __shfl_up(B0,  d);
        float rB1 = __shfl_up(B1,  d);
        if (lane >= d) {
            float n00 = fmaf(A00, r00, A01*r10);
            float n01 = fmaf(A00, r01, A01*r11);
            float n10 = fmaf(A10, r00, A11*r10);
            float n11 = fmaf(A10, r01, A11*r11);
            float nB0 = fmaf(A00, rB0, fmaf(A01, rB1, B0));
            float nB1 = fmaf(A10, rB0, fmaf(A11, rB1, B1));
            A00=n00; A01=n01; A10=n10; A11=n11; B0=nB0; B1=nB1;
        }
    }
    // Exclusive prefix -> x at this segment's start.
    float e00 = __shfl_up(A00, 1);
    float e01 = __shfl_up(A01, 1);
    float e10 = __shfl_up(A10, 1);
    float e11 = __shfl_up(A11, 1);
    float eB0 = __shfl_up(B0,  1);
    float eB1 = __shfl_up(B1,  1);
    float x0 = (s == 0) ? x0i : fmaf(e00, x0i, fmaf(e01, x1i, eB0));
    float x1 = (s == 0) ? x1i : fmaf(e10, x0i, fmaf(e11, x1i, eB1));

    // ---- Phase 2: replay from checkpoint, emit dy_hat into v[].
    vx = vxs; vp = vps; cxp = cxs; f0 = f0s; f1 = f1s;
    #pragma unroll
    for (int j = 0; j < 16; ++j) {
        float yh0, yh1;
        #pragma unroll
        for (int h = 0; h < 2; ++h) {
            float dy0 = h ? v[j].z : v[j].x;
            float yh  = YC * x0;              // dy_hat uses pre-update x
            if (h) yh1 = yh; else yh0 = yh;
            float xi0, xi1, nf0;
            covf_step(vx, vp, cxp, f0, f1, k00, k01, k10, k11, xi0, xi1, nf0);
            float p00 = fmaf(-DTC, xi0, P00c);
            float p10 = fmaf(-DTC, xi1, P10c);
            float r0  = xi0*dy0;
            float r1  = fmaf(DT, nf0, xi1*dy0);
            float nx0 = fmaf(p00, x0, fmaf(P01c, x1, r0));
            float nx1 = fmaf(p10, x0, fmaf(P11c, x1, r1));
            x0 = nx0; x1 = nx1;
        }
        v[j] = make_float4(yh0, 0.f, yh1, 0.f);
    }

    // Store the lane's 256B dy_hat slice NONTEMPORAL (single-use output:
    // bypass L2/L3 write-allocate so dy stays cache-resident across replays).
    float4* dst = reinterpret_cast<float4*>(out + 6*NBATCH)
                + (size_t)b*ROWF4 + s*16;
    #pragma unroll
    for (int j = 0; j < 16; ++j) {
        f4v vv = { v[j].x, v[j].y, v[j].z, v[j].w };
        __builtin_nontemporal_store(vv, (f4v*)(dst + j));
    }

    // Lane 63 finished t=2048: write nstate and fnew.
    if (s == 63) {
        out[b*6+0] = x0; out[b*6+1] = x1;
        out[b*6+2] = vx; out[b*6+3] = vp; out[b*6+4] = cxp;
        out[b*6+5] = t0 + 2.048f;
        float* fo = out + 6*NBATCH + (size_t)NBATCH*NT*2;
        fo[b*2+0] = f0; fo[b*2+1] = f1;
    }
}

// Host: LFT step matrix (Kalman form) ^ 32, computed in double.
static M16 build_m_pow(int log2l)
{
    const double dt = 0.001;
    const double a00 = -0.15, a01 = 6.283185, a10 = -6.283185, a11 = -0.15;
    const double qq = dt * 4.0 * 0.8 * 0.9;
    const double qd = dt * 5.25;
    const double h00 = 1.0 + dt*a00, h01 = dt*a01;
    const double h10 = dt*a10,       h11 = 1.0 + dt*a11;
    const double det = h00*h11 - h01*h10;
    const double t00 = h11/det, t01 = -h10/det, t10 = -h01/det, t11 = h00/det;
    const double g00 = t00*qq, g10 = t10*qq;
    double M[4][4] = {
        { h00 + qd*g00, h01, qd*t00, qd*t01 },
        { h10 + qd*g10, h11, qd*t10, qd*t11 },
        { g00,          0.0, t00,    t01    },
        { g10,          0.0, t10,    t11    },
    };
    for (int it = 0; it < log2l; ++it) {
        double R[4][4];
        for (int i = 0; i < 4; ++i)
            for (int j = 0; j < 4; ++j) {
                double acc = 0.0;
                for (int k = 0; k < 4; ++k) acc += M[i][k]*M[k][j];
                R[i][j] = acc;
            }
        for (int i = 0; i < 4; ++i)
            for (int j = 0; j < 4; ++j) M[i][j] = R[i][j];
    }
    M16 r;
    for (int i = 0; i < 4; ++i)
        for (int j = 0; j < 4; ++j) r.m[i*4+j] = (float)M[i][j];
    return r;
}

extern "C" void kernel_launch(void* const* d_in, const int* in_sizes, int n_in,
                              void* d_out, int out_size, void* d_ws, size_t ws_size,
                              hipStream_t stream)
{
    const float* dy    = (const float*)d_in[0];
    const float* state = (const float*)d_in[1];
    const float* fin   = (const float*)d_in[2];
    const float* kp    = (const float*)d_in[3];
    float* out = (float*)d_out;

    M16 mc = build_m_pow(5);     // ML = M_step^32

    kfused<<<dim3(NBATCH/4), dim3(256), 0, stream>>>(dy, state, fin, kp, mc, out);
}

// Round 16
// 49.845 us; speedup vs baseline: 3.3288x; 3.3288x over previous
//
#include <hip/hip_runtime.h>
#include <cmath>

// GRNN_3547642986522 — B=4096 filters, T=2048 steps. R16 = R11 + table ckpt.
// Math: cov (Riccati) evolves by a CONSTANT LFT per step (Euler == Kalman LFT
// to O(dt^2)); ML = M_step^32 on host in double. x affine given cov; f linear.
// kinit (1 block, 64 thr): thread e -> ws[e*16..]=ML^e (4x4), ws[1024+e*4..]
//   = Mf32^e (2x2). Built once, 5KB, L2-hot for all 1024 blocks.
// kfused: wave = 1 batch, lane = 1 segment (64 segs x 32 steps).
//  - lane s: checkpoint cov/f via 5 f4 table loads + one lft_apply (replaces
//    the ~700-VALU serial matpow chain of R11 — the per-wave latency pole);
//  - phase 1: accumulate segment transfer x_end = X x_start + Q (reads dy);
//  - wave-scan (6 shfl_up) composes 64 affine maps -> x at segment start;
//  - phase 2: replay 32 steps emitting dy_hat; lane 63 writes nstate/fnew.
// Memory: wave covers one contiguous 16KB row; block = 4 rows, XCD-swizzled;
// dy read once (registers, reused both phases); plain (cached) stores.

#define NBATCH 4096
#define NT     2048
#define ROWF4  1024        // float4 per dy row

struct M16 { float m[16]; };

namespace gk {

constexpr float DT   = 0.001f;
constexpr float A00  = -0.15f;
constexpr float A01  = 6.283185f;
constexpr float A10  = -6.283185f;
constexpr float A11  = -0.15f;
constexpr float C0   = 1.6970562748477141f;
constexpr float DD   = 5.25f;

constexpr float P00c = 1.0f + DT*A00;
constexpr float P01c = DT*A01;
constexpr float P10c = DT*A10;
constexpr float P11c = 1.0f + DT*A11;
constexpr float DTC  = DT*C0;
constexpr float QQ   = DT*C0*C0;
constexpr float cVA  = 1.0f + 2.0f*DT*A00;
constexpr float cVB  = 2.0f*DT*A01;
constexpr float cVBn = 2.0f*DT*A10;
constexpr float cVD  = DT*DD;
constexpr float cCA  = 1.0f + DT*(A00+A11);
constexpr float cCB  = DT*A10;
constexpr float cCC  = DT*A01;
constexpr float YC   = C0*DT;

__device__ __forceinline__ void cov_step(float& vx, float& vp, float& cxp)
{
    float a1 = fmaf(-QQ, vx,  cVA);
    float b1 = fmaf(cVB, cxp, cVD);
    float a2 = fmaf(-QQ, cxp, cVBn);
    float b2 = fmaf(a2,  cxp, cVD);
    float a3 = fmaf(-QQ, vx,  cCA);
    float m  = cCC * vp;
    float c3 = fmaf(cCB, vx,  m);
    float nvx = fmaf(a1,  vx,  b1);
    float nvp = fmaf(cVA, vp,  b2);
    float ncx = fmaf(a3,  cxp, c3);
    vx = nvx; vp = nvp; cxp = ncx;
}

__device__ __forceinline__ void covf_step(
    float& vx, float& vp, float& cxp, float& f0, float& f1,
    float k00, float k01, float k10, float k11,
    float& xi0o, float& xi1o, float& nf0o)
{
    float xi0 = C0*vx, xi1 = C0*cxp;
    float nf0 = fmaf(DT, fmaf(k00, f0, k01*f1), f0);
    float nf1 = fmaf(DT, fmaf(k10, f0, k11*f1), f1);
    xi0o = xi0; xi1o = xi1; nf0o = nf0;
    cov_step(vx, vp, cxp);
    f0 = nf0; f1 = nf1;
}

__device__ __forceinline__ void mat4_mul(const float* A, const float* B, float* C)
{
    #pragma unroll
    for (int i = 0; i < 4; ++i)
        #pragma unroll
        for (int j = 0; j < 4; ++j) {
            float acc = A[i*4+0] * B[0*4+j];
            acc = fmaf(A[i*4+1], B[1*4+j], acc);
            acc = fmaf(A[i*4+2], B[2*4+j], acc);
            acc = fmaf(A[i*4+3], B[3*4+j], acc);
            C[i*4+j] = acc;
        }
}

// P -> (E P + F)(G P + H)^-1, P = [[vx,cxp],[cxp,vp]].
__device__ __forceinline__ void lft_apply(const float* m, float& vx, float& vp, float& cxp)
{
    float n00 = fmaf(m[0], vx,  fmaf(m[1], cxp, m[2]));
    float n01 = fmaf(m[0], cxp, fmaf(m[1], vp,  m[3]));
    float n10 = fmaf(m[4], vx,  fmaf(m[5], cxp, m[6]));
    float n11 = fmaf(m[4], cxp, fmaf(m[5], vp,  m[7]));
    float d00 = fmaf(m[8],  vx,  fmaf(m[9],  cxp, m[10]));
    float d01 = fmaf(m[8],  cxp, fmaf(m[9],  vp,  m[11]));
    float d10 = fmaf(m[12], vx,  fmaf(m[13], cxp, m[14]));
    float d11 = fmaf(m[12], cxp, fmaf(m[13], vp,  m[15]));
    float rdet = 1.0f / fmaf(d00, d11, -d01*d10);
    float p00 = fmaf(n00, d11, -n01*d10) * rdet;
    float p01 = fmaf(n01, d00, -n00*d01) * rdet;
    float p10 = fmaf(n10, d11, -n11*d10) * rdet;
    float p11 = fmaf(n11, d00, -n10*d01) * rdet;
    vx = p00; vp = p11; cxp = 0.5f*(p01 + p10);
}

// XCD-aware bijective swizzle (n % 8 == 0).
__device__ __forceinline__ int xcd_swz(int bx, int n)
{
    return (bx & 7) * (n >> 3) + (bx >> 3);
}

} // namespace gk

// ---------------------------------------------------------------- kinit
// Thread e (0..63): ws[e*16..] = ML^e ; ws[1024 + e*4..] = Mf32^e.
__global__ void __launch_bounds__(64, 1)
kinit(const float* __restrict__ kp, M16 mlb, float* __restrict__ ws)
{
    using namespace gk;
    const int e = threadIdx.x;

    float acc[16] = {1,0,0,0, 0,1,0,0, 0,0,1,0, 0,0,0,1};
    float bas[16];
    #pragma unroll
    for (int i = 0; i < 16; ++i) bas[i] = mlb.m[i];
    #pragma unroll
    for (int it = 0; it < 6; ++it) {
        float t[16];
        if ((e >> it) & 1) {
            mat4_mul(acc, bas, t);
            #pragma unroll
            for (int i = 0; i < 16; ++i) acc[i] = t[i];
        }
        if (it < 5) {
            mat4_mul(bas, bas, t);
            #pragma unroll
            for (int i = 0; i < 16; ++i) bas[i] = t[i];
        }
    }
    #pragma unroll
    for (int i = 0; i < 16; ++i) ws[e*16 + i] = acc[i];

    // Mf32 = (I + dt K)^32, then ^e.
    float m00 = fmaf(DT,kp[0],1.f), m01 = DT*kp[1];
    float m10 = DT*kp[2],           m11 = fmaf(DT,kp[3],1.f);
    #pragma unroll
    for (int i = 0; i < 5; ++i) {
        float a = fmaf(m00,m00, m01*m10);
        float q = fmaf(m00,m01, m01*m11);
        float c = fmaf(m10,m00, m11*m10);
        float d = fmaf(m10,m01, m11*m11);
        m00=a; m01=q; m10=c; m11=d;
    }
    float a00=1.f, a01=0.f, a10=0.f, a11=1.f;
    #pragma unroll
    for (int it = 0; it < 6; ++it) {
        if ((e >> it) & 1) {
            float x0 = fmaf(a00,m00, a01*m10);
            float x1 = fmaf(a00,m01, a01*m11);
            float x2 = fmaf(a10,m00, a11*m10);
            float x3 = fmaf(a10,m01, a11*m11);
            a00=x0; a01=x1; a10=x2; a11=x3;
        }
        if (it < 5) {
            float x0 = fmaf(m00,m00, m01*m10);
            float x1 = fmaf(m00,m01, m01*m11);
            float x2 = fmaf(m10,m00, m11*m10);
            float x3 = fmaf(m10,m01, m11*m11);
            m00=x0; m01=x1; m10=x2; m11=x3;
        }
    }
    ws[1024 + e*4 + 0] = a00;  ws[1024 + e*4 + 1] = a01;
    ws[1024 + e*4 + 2] = a10;  ws[1024 + e*4 + 3] = a11;
}

// ------------------------------------------------------------- fused kernel
__global__ void __launch_bounds__(256, 3)
kfused(const float* __restrict__ dy, const float* __restrict__ state,
       const float* __restrict__ fin, const float* __restrict__ kp,
       const float* __restrict__ ws, float* __restrict__ out)
{
    using namespace gk;
    const int lane = threadIdx.x & 63;
    const int wv   = threadIdx.x >> 6;
    const int g    = xcd_swz(blockIdx.x, gridDim.x);   // 1024 blocks
    const int b    = g*4 + wv;                         // wave-uniform batch
    const int s    = lane;                             // lane = segment

    // Load the lane's 256B dy slice FIRST (wave covers contiguous 16KB row).
    const float4* base = reinterpret_cast<const float4*>(dy)
                       + (size_t)b*ROWF4 + s*16;
    float4 v[16];
    #pragma unroll
    for (int j = 0; j < 16; ++j) v[j] = base[j];

    // Lane's checkpoint transforms from the table (L2-hot, 5 f4 loads).
    float m[16];
    {
        const float4* tml = reinterpret_cast<const float4*>(ws) + s*4;
        float4 q0 = tml[0], q1 = tml[1], q2 = tml[2], q3 = tml[3];
        m[0]=q0.x; m[1]=q0.y; m[2]=q0.z;  m[3]=q0.w;
        m[4]=q1.x; m[5]=q1.y; m[6]=q1.z;  m[7]=q1.w;
        m[8]=q2.x; m[9]=q2.y; m[10]=q2.z; m[11]=q2.w;
        m[12]=q3.x; m[13]=q3.y; m[14]=q3.z; m[15]=q3.w;
    }
    const float4 fm = reinterpret_cast<const float4*>(ws + 1024)[s];

    // Wave-uniform small loads (scalarized by compiler).
    const float k00 = kp[0], k01 = kp[1], k10 = kp[2], k11 = kp[3];
    const float x0i = state[b*6+0], x1i = state[b*6+1];
    const float vx0 = state[b*6+2], vp0 = state[b*6+3], cx0 = state[b*6+4];
    const float t0  = state[b*6+5];
    const float f0i = fin[b*2+0],   f1i = fin[b*2+1];

    // Checkpoint cov/f at segment start (one lft_apply — no matpow chain).
    float vx = vx0, vp = vp0, cxp = cx0;
    lft_apply(m, vx, vp, cxp);
    float f0 = fmaf(fm.x, f0i, fm.y*f1i);
    float f1 = fmaf(fm.z, f0i, fm.w*f1i);
    const float vxs = vx, vps = vp, cxs = cxp, f0s = f0, f1s = f1;

    // ---- Phase 1: per-segment affine map x_end = X x_start + Q.
    float X00 = 1.f, X01 = 0.f, X10 = 0.f, X11 = 1.f, Q0 = 0.f, Q1 = 0.f;
    #pragma unroll
    for (int j = 0; j < 16; ++j) {
        #pragma unroll
        for (int h = 0; h < 2; ++h) {
            float dy0 = h ? v[j].z : v[j].x;
            float xi0, xi1, nf0;
            covf_step(vx, vp, cxp, f0, f1, k00, k01, k10, k11, xi0, xi1, nf0);
            float p00 = fmaf(-DTC, xi0, P00c);
            float p10 = fmaf(-DTC, xi1, P10c);
            float r0  = xi0*dy0;
            float r1  = fmaf(DT, nf0, xi1*dy0);
            float nX00 = fmaf(p00, X00, P01c*X10);
            float nX01 = fmaf(p00, X01, P01c*X11);
            float nX10 = fmaf(p10, X00, P11c*X10);
            float nX11 = fmaf(p10, X01, P11c*X11);
            float nQ0  = fmaf(p00, Q0, fmaf(P01c, Q1, r0));
            float nQ1  = fmaf(p10, Q0, fmaf(P11c, Q1, r1));
            X00 = nX00; X01 = nX01; X10 = nX10; X11 = nX11; Q0 = nQ0; Q1 = nQ1;
        }
    }

    // ---- Wave-scan: inclusive prefix composition of the 64 affine maps.
    float A00 = X00, A01 = X01, A10 = X10, A11 = X11, B0 = Q0, B1 = Q1;
    #pragma unroll
    for (int d = 1; d < 64; d <<= 1) {
        float r00 = __shfl_up(A00, d);
        float r01 = __shfl_up(A01, d);
        float r10 = __shfl_up(A10, d);
        float r11 = __shfl_up(A11, d);
        float rB0 = __shfl_up(B0,  d);
        float rB1 = __shfl_up(B1,  d);
        if (lane >= d) {
            float n00 = fmaf(A00, r00, A01*r10);
            float n01 = fmaf(A00, r01, A01*r11);
            float n10 = fmaf(A10, r00, A11*r10);
            float n11 = fmaf(A10, r01, A11*r11);
            float nB0 = fmaf(A00, rB0, fmaf(A01, rB1, B0));
            float nB1 = fmaf(A10, rB0, fmaf(A11, rB1, B1));
            A00=n00; A01=n01; A10=n10; A11=n11; B0=nB0; B1=nB1;
        }
    }
    // Exclusive prefix -> x at this segment's start.
    float e00 = __shfl_up(A00, 1);
    float e01 = __shfl_up(A01, 1);
    float e10 = __shfl_up(A10, 1);
    float e11 = __shfl_up(A11, 1);
    float eB0 = __shfl_up(B0,  1);
    float eB1 = __shfl_up(B1,  1);
    float x0 = (s == 0) ? x0i : fmaf(e00, x0i, fmaf(e01, x1i, eB0));
    float x1 = (s == 0) ? x1i : fmaf(e10, x0i, fmaf(e11, x1i, eB1));

    // ---- Phase 2: replay from checkpoint, emit dy_hat into v[].
    vx = vxs; vp = vps; cxp = cxs; f0 = f0s; f1 = f1s;
    #pragma unroll
    for (int j = 0; j < 16; ++j) {
        float yh0, yh1;
        #pragma unroll
        for (int h = 0; h < 2; ++h) {
            float dy0 = h ? v[j].z : v[j].x;
            float yh  = YC * x0;              // dy_hat uses pre-update x
            if (h) yh1 = yh; else yh0 = yh;
            float xi0, xi1, nf0;
            covf_step(vx, vp, cxp, f0, f1, k00, k01, k10, k11, xi0, xi1, nf0);
            float p00 = fmaf(-DTC, xi0, P00c);
            float p10 = fmaf(-DTC, xi1, P10c);
            float r0  = xi0*dy0;
            float r1  = fmaf(DT, nf0, xi1*dy0);
            float nx0 = fmaf(p00, x0, fmaf(P01c, x1, r0));
            float nx1 = fmaf(p10, x0, fmaf(P11c, x1, r1));
            x0 = nx0; x1 = nx1;
        }
        v[j] = make_float4(yh0, 0.f, yh1, 0.f);
    }

    // Store the lane's 256B dy_hat slice (plain cached stores — R15 showed
    // nontemporal f4 stores 3x-amplify write traffic on gfx950).
    float4* dst = reinterpret_cast<float4*>(out + 6*NBATCH)
                + (size_t)b*ROWF4 + s*16;
    #pragma unroll
    for (int j = 0; j < 16; ++j) dst[j] = v[j];

    // Lane 63 finished t=2048: write nstate and fnew.
    if (s == 63) {
        out[b*6+0] = x0; out[b*6+1] = x1;
        out[b*6+2] = vx; out[b*6+3] = vp; out[b*6+4] = cxp;
        out[b*6+5] = t0 + 2.048f;
        float* fo = out + 6*NBATCH + (size_t)NBATCH*NT*2;
        fo[b*2+0] = f0; fo[b*2+1] = f1;
    }
}

// Host: LFT step matrix (Kalman form) ^ 32, computed in double.
static M16 build_m_pow(int log2l)
{
    const double dt = 0.001;
    const double a00 = -0.15, a01 = 6.283185, a10 = -6.283185, a11 = -0.15;
    const double qq = dt * 4.0 * 0.8 * 0.9;
    const double qd = dt * 5.25;
    const double h00 = 1.0 + dt*a00, h01 = dt*a01;
    const double h10 = dt*a10,       h11 = 1.0 + dt*a11;
    const double det = h00*h11 - h01*h10;
    const double t00 = h11/det, t01 = -h10/det, t10 = -h01/det, t11 = h00/det;
    const double g00 = t00*qq, g10 = t10*qq;
    double M[4][4] = {
        { h00 + qd*g00, h01, qd*t00, qd*t01 },
        { h10 + qd*g10, h11, qd*t10, qd*t11 },
        { g00,          0.0, t00,    t01    },
        { g10,          0.0, t10,    t11    },
    };
    for (int it = 0; it < log2l; ++it) {
        double R[4][4];
        for (int i = 0; i < 4; ++i)
            for (int j = 0; j < 4; ++j) {
                double acc = 0.0;
                for (int k = 0; k < 4; ++k) acc += M[i][k]*M[k][j];
                R[i][j] = acc;
            }
        for (int i = 0; i < 4; ++i)
            for (int j = 0; j < 4; ++j) M[i][j] = R[i][j];
    }
    M16 r;
    for (int i = 0; i < 4; ++i)
        for (int j = 0; j < 4; ++j) r.m[i*4+j] = (float)M[i][j];
    return r;
}

extern "C" void kernel_launch(void* const* d_in, const int* in_sizes, int n_in,
                              void* d_out, int out_size, void* d_ws, size_t ws_size,
                              hipStream_t stream)
{
    const float* dy    = (const float*)d_in[0];
    const float* state = (const float*)d_in[1];
    const float* fin   = (const float*)d_in[2];
    const float* kp    = (const float*)d_in[3];
    float* out = (float*)d_out;
    float* ws  = (float*)d_ws;   // 5 KB table

    M16 mlb = build_m_pow(5);    // ML = M_step^32

    kinit<<<dim3(1), dim3(64), 0, stream>>>(kp, mlb, ws);
    kfused<<<dim3(NBATCH/4), dim3(256), 0, stream>>>(dy, state, fin, kp, ws, out);
}

// Round 17
// 42.053 us; speedup vs baseline: 3.9456x; 1.1853x over previous
//
#include <hip/hip_runtime.h>
#include <cmath>

// GRNN_3547642986522 — B=4096 filters, T=2048 steps. R17 = R11 + in-loop stores.
// Math: cov (Riccati) evolves by a CONSTANT LFT per step (Euler == Kalman LFT
// to O(dt^2)); host computes ML = M_step^32 in double. x is affine given cov;
// f linear; t closed-form.
// Mapping: wave = 1 batch, lane = 1 segment (64 segs x 32 steps).
//  - lane s: checkpoint cov/f at t=32s via per-lane binary matpow of ML
//    (hidden under the 16-load flight);
//  - phase 1: accumulate segment transfer x_end = X x_start + Q (reads dy);
//  - wave-scan (6 shfl_up) composes the 64 affine maps -> x at segment start;
//  - phase 2: replay 32 steps; EACH 16B dy_hat slice stores IMMEDIATELY
//    (spreads the 16KB/wave write burst across the dependency-bound compute
//    instead of a terminal burst + exit drain); lane 63 writes nstate/fnew.
// Memory: wave covers one contiguous 16KB row; block = 4 rows, XCD-swizzled.
// dy read once (registers, reused both phases). Plain cached stores (R15:
// nontemporal f4 stores 3x-amplify writes on gfx950).

#define NBATCH 4096
#define NT     2048
#define ROWF4  1024        // float4 per dy row

struct M16 { float m[16]; };

namespace gk {

constexpr float DT   = 0.001f;
constexpr float A00  = -0.15f;
constexpr float A01  = 6.283185f;
constexpr float A10  = -6.283185f;
constexpr float A11  = -0.15f;
constexpr float C0   = 1.6970562748477141f;
constexpr float DD   = 5.25f;

constexpr float P00c = 1.0f + DT*A00;
constexpr float P01c = DT*A01;
constexpr float P10c = DT*A10;
constexpr float P11c = 1.0f + DT*A11;
constexpr float DTC  = DT*C0;
constexpr float QQ   = DT*C0*C0;
constexpr float cVA  = 1.0f + 2.0f*DT*A00;
constexpr float cVB  = 2.0f*DT*A01;
constexpr float cVBn = 2.0f*DT*A10;
constexpr float cVD  = DT*DD;
constexpr float cCA  = 1.0f + DT*(A00+A11);
constexpr float cCB  = DT*A10;
constexpr float cCC  = DT*A01;
constexpr float YC   = C0*DT;

__device__ __forceinline__ void cov_step(float& vx, float& vp, float& cxp)
{
    float a1 = fmaf(-QQ, vx,  cVA);
    float b1 = fmaf(cVB, cxp, cVD);
    float a2 = fmaf(-QQ, cxp, cVBn);
    float b2 = fmaf(a2,  cxp, cVD);
    float a3 = fmaf(-QQ, vx,  cCA);
    float m  = cCC * vp;
    float c3 = fmaf(cCB, vx,  m);
    float nvx = fmaf(a1,  vx,  b1);
    float nvp = fmaf(cVA, vp,  b2);
    float ncx = fmaf(a3,  cxp, c3);
    vx = nvx; vp = nvp; cxp = ncx;
}

__device__ __forceinline__ void covf_step(
    float& vx, float& vp, float& cxp, float& f0, float& f1,
    float k00, float k01, float k10, float k11,
    float& xi0o, float& xi1o, float& nf0o)
{
    float xi0 = C0*vx, xi1 = C0*cxp;
    float nf0 = fmaf(DT, fmaf(k00, f0, k01*f1), f0);
    float nf1 = fmaf(DT, fmaf(k10, f0, k11*f1), f1);
    xi0o = xi0; xi1o = xi1; nf0o = nf0;
    cov_step(vx, vp, cxp);
    f0 = nf0; f1 = nf1;
}

__device__ __forceinline__ void mat4_mul(const float* A, const float* B, float* C)
{
    #pragma unroll
    for (int i = 0; i < 4; ++i)
        #pragma unroll
        for (int j = 0; j < 4; ++j) {
            float acc = A[i*4+0] * B[0*4+j];
            acc = fmaf(A[i*4+1], B[1*4+j], acc);
            acc = fmaf(A[i*4+2], B[2*4+j], acc);
            acc = fmaf(A[i*4+3], B[3*4+j], acc);
            C[i*4+j] = acc;
        }
}

// P -> (E P + F)(G P + H)^-1, P = [[vx,cxp],[cxp,vp]].
__device__ __forceinline__ void lft_apply(const float* m, float& vx, float& vp, float& cxp)
{
    float n00 = fmaf(m[0], vx,  fmaf(m[1], cxp, m[2]));
    float n01 = fmaf(m[0], cxp, fmaf(m[1], vp,  m[3]));
    float n10 = fmaf(m[4], vx,  fmaf(m[5], cxp, m[6]));
    float n11 = fmaf(m[4], cxp, fmaf(m[5], vp,  m[7]));
    float d00 = fmaf(m[8],  vx,  fmaf(m[9],  cxp, m[10]));
    float d01 = fmaf(m[8],  cxp, fmaf(m[9],  vp,  m[11]));
    float d10 = fmaf(m[12], vx,  fmaf(m[13], cxp, m[14]));
    float d11 = fmaf(m[12], cxp, fmaf(m[13], vp,  m[15]));
    float rdet = 1.0f / fmaf(d00, d11, -d01*d10);
    float p00 = fmaf(n00, d11, -n01*d10) * rdet;
    float p01 = fmaf(n01, d00, -n00*d01) * rdet;
    float p10 = fmaf(n10, d11, -n11*d10) * rdet;
    float p11 = fmaf(n11, d00, -n10*d01) * rdet;
    vx = p00; vp = p11; cxp = 0.5f*(p01 + p10);
}

// Per-lane checkpoint at segment start s: cov via lft(ML^s), f via Mf32^s.
__device__ __forceinline__ void seg_checkpoint(
    const M16& ml, int s,
    float k00, float k01, float k10, float k11,
    float& vx, float& vp, float& cxp, float& f0, float& f1)
{
    float acc[16] = {1,0,0,0, 0,1,0,0, 0,0,1,0, 0,0,0,1};
    float bas[16];
    #pragma unroll
    for (int i = 0; i < 16; ++i) bas[i] = ml.m[i];
    #pragma unroll
    for (int it = 0; it < 6; ++it) {
        float t[16];
        if ((s >> it) & 1) {
            mat4_mul(acc, bas, t);
            #pragma unroll
            for (int i = 0; i < 16; ++i) acc[i] = t[i];
        }
        if (it < 5) {
            mat4_mul(bas, bas, t);
            #pragma unroll
            for (int i = 0; i < 16; ++i) bas[i] = t[i];
        }
    }
    lft_apply(acc, vx, vp, cxp);

    float m00 = fmaf(DT,k00,1.f), m01 = DT*k01;
    float m10 = DT*k10,           m11 = fmaf(DT,k11,1.f);
    #pragma unroll
    for (int i = 0; i < 5; ++i) {            // (I + dt K)^32
        float a = fmaf(m00,m00, m01*m10);
        float q = fmaf(m00,m01, m01*m11);
        float c = fmaf(m10,m00, m11*m10);
        float d = fmaf(m10,m01, m11*m11);
        m00=a; m01=q; m10=c; m11=d;
    }
    float a00=1.f, a01=0.f, a10=0.f, a11=1.f;
    #pragma unroll
    for (int it = 0; it < 6; ++it) {
        if ((s >> it) & 1) {
            float x0 = fmaf(a00,m00, a01*m10);
            float x1 = fmaf(a00,m01, a01*m11);
            float x2 = fmaf(a10,m00, a11*m10);
            float x3 = fmaf(a10,m01, a11*m11);
            a00=x0; a01=x1; a10=x2; a11=x3;
        }
        if (it < 5) {
            float x0 = fmaf(m00,m00, m01*m10);
            float x1 = fmaf(m00,m01, m01*m11);
            float x2 = fmaf(m10,m00, m11*m10);
            float x3 = fmaf(m10,m01, m11*m11);
            m00=x0; m01=x1; m10=x2; m11=x3;
        }
    }
    float nf0 = fmaf(a00, f0, a01*f1);
    float nf1 = fmaf(a10, f0, a11*f1);
    f0 = nf0; f1 = nf1;
}

// XCD-aware bijective swizzle (n % 8 == 0).
__device__ __forceinline__ int xcd_swz(int bx, int n)
{
    return (bx & 7) * (n >> 3) + (bx >> 3);
}

} // namespace gk

// ------------------------------------------------------------- fused kernel
__global__ void __launch_bounds__(256, 3)
kfused(const float* __restrict__ dy, const float* __restrict__ state,
       const float* __restrict__ fin, const float* __restrict__ kp,
       M16 mc, float* __restrict__ out)
{
    using namespace gk;
    const int lane = threadIdx.x & 63;
    const int wv   = threadIdx.x >> 6;
    const int g    = xcd_swz(blockIdx.x, gridDim.x);   // 1024 blocks
    const int b    = g*4 + wv;                         // wave-uniform batch
    const int s    = lane;                             // lane = segment

    // Wave-uniform small loads (scalarized by compiler).
    const float k00 = kp[0], k01 = kp[1], k10 = kp[2], k11 = kp[3];
    const float x0i = state[b*6+0], x1i = state[b*6+1];
    const float vx0 = state[b*6+2], vp0 = state[b*6+3], cx0 = state[b*6+4];
    const float t0  = state[b*6+5];
    const float f0i = fin[b*2+0],   f1i = fin[b*2+1];

    // Load the lane's 256B dy slice (wave covers one contiguous 16KB row).
    const float4* base = reinterpret_cast<const float4*>(dy)
                       + (size_t)b*ROWF4 + s*16;
    float4 v[16];
    #pragma unroll
    for (int j = 0; j < 16; ++j) v[j] = base[j];

    // Checkpoint cov/f at segment start (hidden under load flight).
    float vx = vx0, vp = vp0, cxp = cx0, f0 = f0i, f1 = f1i;
    seg_checkpoint(mc, s, k00, k01, k10, k11, vx, vp, cxp, f0, f1);
    const float vxs = vx, vps = vp, cxs = cxp, f0s = f0, f1s = f1;

    // ---- Phase 1: per-segment affine map x_end = X x_start + Q.
    float X00 = 1.f, X01 = 0.f, X10 = 0.f, X11 = 1.f, Q0 = 0.f, Q1 = 0.f;
    #pragma unroll
    for (int j = 0; j < 16; ++j) {
        #pragma unroll
        for (int h = 0; h < 2; ++h) {
            float dy0 = h ? v[j].z : v[j].x;
            float xi0, xi1, nf0;
            covf_step(vx, vp, cxp, f0, f1, k00, k01, k10, k11, xi0, xi1, nf0);
            float p00 = fmaf(-DTC, xi0, P00c);
            float p10 = fmaf(-DTC, xi1, P10c);
            float r0  = xi0*dy0;
            float r1  = fmaf(DT, nf0, xi1*dy0);
            float nX00 = fmaf(p00, X00, P01c*X10);
            float nX01 = fmaf(p00, X01, P01c*X11);
            float nX10 = fmaf(p10, X00, P11c*X10);
            float nX11 = fmaf(p10, X01, P11c*X11);
            float nQ0  = fmaf(p00, Q0, fmaf(P01c, Q1, r0));
            float nQ1  = fmaf(p10, Q0, fmaf(P11c, Q1, r1));
            X00 = nX00; X01 = nX01; X10 = nX10; X11 = nX11; Q0 = nQ0; Q1 = nQ1;
        }
    }

    // ---- Wave-scan: inclusive prefix composition of the 64 affine maps.
    float A00 = X00, A01 = X01, A10 = X10, A11 = X11, B0 = Q0, B1 = Q1;
    #pragma unroll
    for (int d = 1; d < 64; d <<= 1) {
        float r00 = __shfl_up(A00, d);
        float r01 = __shfl_up(A01, d);
        float r10 = __shfl_up(A10, d);
        float r11 = __shfl_up(A11, d);
        float rB0 = __shfl_up(B0,  d);
        float rB1 = __shfl_up(B1,  d);
        if (lane >= d) {
            float n00 = fmaf(A00, r00, A01*r10);
            float n01 = fmaf(A00, r01, A01*r11);
            float n10 = fmaf(A10, r00, A11*r10);
            float n11 = fmaf(A10, r01, A11*r11);
            float nB0 = fmaf(A00, rB0, fmaf(A01, rB1, B0));
            float nB1 = fmaf(A10, rB0, fmaf(A11, rB1, B1));
            A00=n00; A01=n01; A10=n10; A11=n11; B0=nB0; B1=nB1;
        }
    }
    // Exclusive prefix -> x at this segment's start.
    float e00 = __shfl_up(A00, 1);
    float e01 = __shfl_up(A01, 1);
    float e10 = __shfl_up(A10, 1);
    float e11 = __shfl_up(A11, 1);
    float eB0 = __shfl_up(B0,  1);
    float eB1 = __shfl_up(B1,  1);
    float x0 = (s == 0) ? x0i : fmaf(e00, x0i, fmaf(e01, x1i, eB0));
    float x1 = (s == 0) ? x1i : fmaf(e10, x0i, fmaf(e11, x1i, eB1));

    // ---- Phase 2: replay from checkpoint; store each dy_hat slice as soon
    // as computed (overlaps write drain with remaining dependency chain).
    float4* dst = reinterpret_cast<float4*>(out + 6*NBATCH)
                + (size_t)b*ROWF4 + s*16;
    vx = vxs; vp = vps; cxp = cxs; f0 = f0s; f1 = f1s;
    #pragma unroll
    for (int j = 0; j < 16; ++j) {
        float yh0, yh1;
        #pragma unroll
        for (int h = 0; h < 2; ++h) {
            float dy0 = h ? v[j].z : v[j].x;
            float yh  = YC * x0;              // dy_hat uses pre-update x
            if (h) yh1 = yh; else yh0 = yh;
            float xi0, xi1, nf0;
            covf_step(vx, vp, cxp, f0, f1, k00, k01, k10, k11, xi0, xi1, nf0);
            float p00 = fmaf(-DTC, xi0, P00c);
            float p10 = fmaf(-DTC, xi1, P10c);
            float r0  = xi0*dy0;
            float r1  = fmaf(DT, nf0, xi1*dy0);
            float nx0 = fmaf(p00, x0, fmaf(P01c, x1, r0));
            float nx1 = fmaf(p10, x0, fmaf(P11c, x1, r1));
            x0 = nx0; x1 = nx1;
        }
        dst[j] = make_float4(yh0, 0.f, yh1, 0.f);   // immediate store
    }

    // Lane 63 finished t=2048: write nstate and fnew.
    if (s == 63) {
        out[b*6+0] = x0; out[b*6+1] = x1;
        out[b*6+2] = vx; out[b*6+3] = vp; out[b*6+4] = cxp;
        out[b*6+5] = t0 + 2.048f;
        float* fo = out + 6*NBATCH + (size_t)NBATCH*NT*2;
        fo[b*2+0] = f0; fo[b*2+1] = f1;
    }
}

// Host: LFT step matrix (Kalman form) ^ 32, computed in double.
static M16 build_m_pow(int log2l)
{
    const double dt = 0.001;
    const double a00 = -0.15, a01 = 6.283185, a10 = -6.283185, a11 = -0.15;
    const double qq = dt * 4.0 * 0.8 * 0.9;
    const double qd = dt * 5.25;
    const double h00 = 1.0 + dt*a00, h01 = dt*a01;
    const double h10 = dt*a10,       h11 = 1.0 + dt*a11;
    const double det = h00*h11 - h01*h10;
    const double t00 = h11/det, t01 = -h10/det, t10 = -h01/det, t11 = h00/det;
    const double g00 = t00*qq, g10 = t10*qq;
    double M[4][4] = {
        { h00 + qd*g00, h01, qd*t00, qd*t01 },
        { h10 + qd*g10, h11, qd*t10, qd*t11 },
        { g00,          0.0, t00,    t01    },
        { g10,          0.0, t10,    t11    },
    };
    for (int it = 0; it < log2l; ++it) {
        double R[4][4];
        for (int i = 0; i < 4; ++i)
            for (int j = 0; j < 4; ++j) {
                double acc = 0.0;
                for (int k = 0; k < 4; ++k) acc += M[i][k]*M[k][j];
                R[i][j] = acc;
            }
        for (int i = 0; i < 4; ++i)
            for (int j = 0; j < 4; ++j) M[i][j] = R[i][j];
    }
    M16 r;
    for (int i = 0; i < 4; ++i)
        for (int j = 0; j < 4; ++j) r.m[i*4+j] = (float)M[i][j];
    return r;
}

extern "C" void kernel_launch(void* const* d_in, const int* in_sizes, int n_in,
                              void* d_out, int out_size, void* d_ws, size_t ws_size,
                              hipStream_t stream)
{
    const float* dy    = (const float*)d_in[0];
    const float* state = (const float*)d_in[1];
    const float* fin   = (const float*)d_in[2];
    const float* kp    = (const float*)d_in[3];
    float* out = (float*)d_out;

    M16 mc = build_m_pow(5);     // ML = M_step^32

    kfused<<<dim3(NBATCH/4), dim3(256), 0, stream>>>(dy, state, fin, kp, mc, out);
}